// Round 8
// baseline (420.665 us; speedup 1.0000x reference)
//
#include <hip/hip_runtime.h>
#include <hip/hip_bf16.h>
#include <cstdint>
#include <cstddef>

#define E_EDGES 320000
#define NN 10000
#define NRELS 40
#define NB 30
#define HID 100
#define NHTOT (NN*HID)       // 1,000,000
#define R2 41                // 40 rels + root2 slot
#define KTOT 4224            // 41*100 = 4100 packed, padded to 33*128
#define NROWS_PAD 10048      // 157 blocks * 64 rows
#define SPLITK 4             // 132 kb-steps -> 33 per gy
#define KB_PER 33
#define RSPLIT 2
#define RPB (NRELS/RSPLIT)   // 20 rels per pass

typedef short bf16x8 __attribute__((ext_vector_type(8)));
typedef float f32x4 __attribute__((ext_vector_type(4)));
typedef float f32x2 __attribute__((ext_vector_type(2)));

__device__ inline ushort f2bf(float f) {
  uint x = __float_as_uint(f);
  return (ushort)((x + 0x7fffu + ((x >> 16) & 1u)) >> 16);
}
__device__ inline float bflo(uint u) { return __uint_as_float(u << 16); }
__device__ inline float bfhi(uint u) { return __uint_as_float(u & 0xffff0000u); }

__device__ inline void gload16(const void* g, void* l) {
  __builtin_amdgcn_global_load_lds(
      (const __attribute__((address_space(1))) void*)g,
      (__attribute__((address_space(3))) void*)l, 16, 0, 0);
}

// ---------------------------------------------------------------- edge meta
__global__ void k_count(const int* __restrict__ dst, const int* __restrict__ et,
                        int* __restrict__ cnt_nr, int* __restrict__ deg) {
  int e = blockIdx.x * blockDim.x + threadIdx.x;
  if (e >= E_EDGES) return;
  int d = dst[e], r = et[e];
  atomicAdd(&cnt_nr[d * NRELS + r], 1);
  atomicAdd(&deg[d], 1);
}

__global__ void k_scan(const int* __restrict__ deg, int* __restrict__ rowptr) {
  __shared__ int ssum[256];
  int t = threadIdx.x;
  const int per = (NN + 255) / 256;
  int base = t * per;
  int s = 0;
  for (int k = 0; k < per; ++k) { int i = base + k; if (i < NN) s += deg[i]; }
  ssum[t] = s; __syncthreads();
  for (int off = 1; off < 256; off <<= 1) {
    int v = (t >= off) ? ssum[t - off] : 0;
    __syncthreads();
    ssum[t] += v;
    __syncthreads();
  }
  int pre = (t == 0) ? 0 : ssum[t - 1];
  for (int k = 0; k < per; ++k) {
    int i = base + k;
    if (i < NN) { rowptr[i] = pre; pre += deg[i]; }
  }
  if (t == 255) rowptr[NN] = ssum[255];
}

__global__ void k_bucket(const int* __restrict__ src, const int* __restrict__ dst,
                         const int* __restrict__ et, const int* __restrict__ rowptr,
                         int* __restrict__ fill, int* __restrict__ ebuf) {
  int e = blockIdx.x * blockDim.x + threadIdx.x;
  if (e >= E_EDGES) return;
  int d = dst[e];
  int pos = rowptr[d] + atomicAdd(&fill[d], 1);
  ebuf[pos] = (src[e] << 6) | et[e];
}

// ---------------------------------------------------------------- W1 (bf16)
// r-split (20 rels/pass, 20 f32x2 accs) + PACKED fp32 FMA: acc += {c,c} * v
// emits v_pk_fma_f32 (dual fp32/instr) -> halves the 61us scalar-VALU cost.
__global__ __launch_bounds__(256) void k_w1b(const float* __restrict__ comp1,
                                             const float* __restrict__ basis1,
                                             uint* __restrict__ W1bf) {
  __shared__ float sct[NB][RPB];   // comp1 chunk transposed: [b][r_local]
  int t = threadIdx.x;
  int rbase = blockIdx.y * RPB;
  for (int i = t; i < RPB * NB; i += 256) {
    int r = i / NB, b = i - r * NB;
    sct[b][r] = comp1[(rbase + r) * NB + b];
  }
  __syncthreads();
  int i2 = blockIdx.x * 256 + t;
  if (i2 >= NHTOT / 2) return;
  f32x2 acc[RPB];
#pragma unroll
  for (int r = 0; r < RPB; ++r) acc[r] = (f32x2){0.f, 0.f};
  for (int b = 0; b < NB; ++b) {
    f32x2 v = ((const f32x2*)basis1)[(size_t)b * (NHTOT / 2) + i2];
#pragma unroll
    for (int r4 = 0; r4 < RPB / 4; ++r4) {
      float4 c = *(const float4*)&sct[b][r4 * 4];   // broadcast ds_read_b128
      acc[r4*4+0] += (f32x2){c.x, c.x} * v;
      acc[r4*4+1] += (f32x2){c.y, c.y} * v;
      acc[r4*4+2] += (f32x2){c.z, c.z} * v;
      acc[r4*4+3] += (f32x2){c.w, c.w} * v;
    }
  }
#pragma unroll
  for (int r = 0; r < RPB; ++r)
    W1bf[(size_t)(rbase + r) * (NHTOT / 2) + i2] =
        (uint)f2bf(acc[r].x) | ((uint)f2bf(acc[r].y) << 16);
}

// ---------------------------------------------------------------- W2 fp32 then packed Bt bf16
__global__ void k_w2(const float* __restrict__ comp2, const float* __restrict__ basis2,
                     float* __restrict__ W2f) {
  int i = blockIdx.x * 256 + threadIdx.x;
  if (i >= HID * HID) return;
  float v[NB];
#pragma unroll
  for (int b = 0; b < NB; ++b) v[b] = basis2[b * HID * HID + i];
  for (int r = 0; r < NRELS; ++r) {
    float a = 0.f;
#pragma unroll
    for (int b = 0; b < NB; ++b) a += comp2[r * NB + b] * v[b];
    W2f[r * HID * HID + i] = a;
  }
}

// Bt[col][kk] packed K: kk = r*100 + k  (r<40: W2f[r][k][col], r==40: root2[k][col])
__global__ void k_bt(const float* __restrict__ W2f, const float* __restrict__ root2,
                     ushort* __restrict__ Bt) {
  int i = blockIdx.x * 256 + threadIdx.x;
  if (i >= 112 * KTOT) return;
  int col = i / KTOT, kk = i - col * KTOT;
  float v = 0.f;
  if (kk < R2 * HID && col < HID) {
    int r = kk / HID, k = kk - r * HID;
    v = (r < NRELS) ? W2f[(r * HID + k) * HID + col] : root2[k * HID + col];
  }
  Bt[i] = f2bf(v);
}

// ---------------------------------------------------------------- conv1 aggregate
// 5 edge-groups x 50 channel-threads; register partials + LDS reduce.
__global__ __launch_bounds__(256) void k_agg1(const int* __restrict__ rowptr,
                                              const int* __restrict__ ebuf,
                                              const int* __restrict__ cnt_nr,
                                              const uint* __restrict__ W1bf,
                                              const float* __restrict__ root1,
                                              const float* __restrict__ bias1,
                                              float* __restrict__ h) {
  __shared__ float red[5][2][50];
  int n = blockIdx.x, t = threadIdx.x;
  int g = t / 50, c = t - g * 50;
  if (g < 5) {
    float a0 = 0.f, a1 = 0.f;
    int beg = rowptr[n], end = rowptr[n + 1];
    for (int j = beg + g; j < end; j += 5) {
      int pk = ebuf[j];
      int r = pk & 63, s = pk >> 6;
      float cf = 1.0f / (float)cnt_nr[n * NRELS + r];
      uint u = W1bf[(size_t)(r * NN + s) * 50 + c];
      a0 += cf * bflo(u);
      a1 += cf * bfhi(u);
    }
    red[g][0][c] = a0;
    red[g][1][c] = a1;
  }
  __syncthreads();
  if (t < 50) {
    float a0 = red[0][0][t] + red[1][0][t] + red[2][0][t] + red[3][0][t] + red[4][0][t];
    float a1 = red[0][1][t] + red[1][1][t] + red[2][1][t] + red[3][1][t] + red[4][1][t];
    int c0 = 2 * t, c1 = 2 * t + 1;
    float v0 = a0 + root1[n * HID + c0] + bias1[c0];
    float v1 = a1 + root1[n * HID + c1] + bias1[c1];
    h[n * HID + c0] = v0 > 0.f ? v0 : 0.f;
    h[n * HID + c1] = v1 > 0.f ? v1 : 0.f;
  }
}

// ---------------------------------------------------------------- hbar (packed bf16 rows)
// Edge-parallel: 5 groups x 100 channels; no-return ds_add_f32 atomics kill
// the serial LDS RMW chain (r7: 78us latency-bound at 1 edge-pair/iter).
__global__ __launch_bounds__(512) void k_hbar(const int* __restrict__ rowptr,
                                              const int* __restrict__ ebuf,
                                              const int* __restrict__ cnt_nr,
                                              const float* __restrict__ h,
                                              uint* __restrict__ hbar) { // [NROWS_PAD][KTOT/2]
  __shared__ float acc[NRELS][HID];   // 16 KB
  int n = blockIdx.x, t = threadIdx.x;
  for (int i = t; i < NRELS * HID; i += 512) ((float*)acc)[i] = 0.f;
  __syncthreads();
  int g = t / HID, c = t - g * HID;   // 5 groups (t<500)
  if (g < 5) {
    int beg = rowptr[n], end = rowptr[n + 1];
    for (int j = beg + g; j < end; j += 5) {
      int pk = ebuf[j];
      atomicAdd(&acc[pk & 63][c], h[(size_t)(pk >> 6) * HID + c]);
    }
  }
  __syncthreads();
  uint* orow = hbar + (size_t)n * (KTOT / 2);
  for (int i = t; i < KTOT / 2; i += 512) {
    float v0 = 0.f, v1 = 0.f;
    if (i < R2 * 50) {
      int r = i / 50;
      int kk = (i - r * 50) * 2;
      if (r < NRELS) {
        int cc = cnt_nr[n * NRELS + r];
        float coef = cc ? 1.0f / (float)cc : 0.f;
        v0 = acc[r][kk] * coef;
        v1 = acc[r][kk + 1] * coef;
      } else {
        v0 = h[n * HID + kk];
        v1 = h[n * HID + kk + 1];
      }
    }
    orow[i] = (uint)f2bf(v0) | ((uint)f2bf(v1) << 16);
  }
}

// ---------------------------------------------------------------- split-K MFMA GEMM
// 2-phase double-buffered LDS pipeline (guide §5.5 T3-minimum).
__global__ __launch_bounds__(256) void k_gemm(const ushort* __restrict__ hbar,
                                              const ushort* __restrict__ Bt,
                                              float* __restrict__ part) {
  __shared__ char lds[2][12288];
  int t = threadIdx.x;
  int wid = t >> 6, l = t & 63;
  int lrow = l & 15, g16 = l >> 4;
  int kb0 = blockIdx.y * KB_PER;
  int row0 = blockIdx.x * 64;

  f32x4 acc[7];
#pragma unroll
  for (int j = 0; j < 7; ++j) acc[j] = (f32x4){0.f, 0.f, 0.f, 0.f};

  auto stage = [&](int p, int buf) {
    int kbg = kb0 + p;
#pragma unroll
    for (int ci = 0; ci < 3; ++ci) {
      int qb = (wid * 3 + ci) * 64;
      int q = qb + l;
      const ushort* g;
      if (q < 448) {                       // B chunk
        int col = q >> 2, c = q & 3;
        g = Bt + (size_t)col * KTOT + kbg * 32 + c * 8;
      } else if (q < 704) {                // A chunk
        int qq = q - 448;
        int row = qq >> 2, c = qq & 3;
        g = hbar + (size_t)(row0 + row) * KTOT + kbg * 32 + c * 8;
      } else {                             // pad
        g = Bt;
      }
      gload16(g, &lds[buf][(size_t)qb * 16]);
    }
  };

  stage(0, 0);
  __syncthreads();

  int cur = 0;
  for (int p = 0; p < KB_PER; ++p) {
    if (p + 1 < KB_PER) stage(p + 1, cur ^ 1);
    const char* base = lds[cur];
    bf16x8 a = *(const bf16x8*)(base + 7168 + (wid * 16 + lrow) * 64 + g16 * 16);
#pragma unroll
    for (int j = 0; j < 7; ++j) {
      bf16x8 b = *(const bf16x8*)(base + (j * 16 + lrow) * 64 + g16 * 16);
      acc[j] = __builtin_amdgcn_mfma_f32_16x16x32_bf16(a, b, acc[j], 0, 0, 0);
    }
    __syncthreads();
    cur ^= 1;
  }

  float* pp = part + (size_t)blockIdx.y * NROWS_PAD * 112;
  int srow = row0 + wid * 16 + g16 * 4;
#pragma unroll
  for (int j = 0; j < 7; ++j) {
    int col = j * 16 + lrow;
#pragma unroll
    for (int v = 0; v < 4; ++v)
      pp[(size_t)(srow + v) * 112 + col] = acc[j][v];
  }
}

// reduce partials + bias
__global__ void k_red(const float* __restrict__ part, const float* __restrict__ bias2,
                      float* __restrict__ xout) {
  int i = blockIdx.x * 256 + threadIdx.x;
  if (i >= NHTOT) return;
  int n = i / HID, c = i - n * HID;
  float s = bias2[c];
#pragma unroll
  for (int g = 0; g < SPLITK; ++g)
    s += part[(size_t)g * NROWS_PAD * 112 + (size_t)n * 112 + c];
  xout[i] = s;
}

// ---------------------------------------------------------------- rel_embedded
__global__ void k_emb(const float4* __restrict__ emb, const int* __restrict__ et,
                      float4* __restrict__ out2) {
  int i = blockIdx.x * 256 + threadIdx.x;
  if (i >= E_EDGES * 25) return;
  int e = i / 25, q = i - e * 25;
  int r = et[e];
  float4 v;
  if (r == 0) { v.x = 0.f; v.y = 0.f; v.z = 0.f; v.w = 0.f; }
  else v = emb[r * 25 + q];
  out2[i] = v;
}

// ---------------------------------------------------------------- launch
extern "C" void kernel_launch(void* const* d_in, const int* in_sizes, int n_in,
                              void* d_out, int out_size, void* d_ws, size_t ws_size,
                              hipStream_t stream) {
  (void)in_sizes; (void)n_in; (void)out_size; (void)d_ws; (void)ws_size;

  const float* comp1  = (const float*)d_in[0];
  const float* basis1 = (const float*)d_in[1];
  const float* root1  = (const float*)d_in[2];
  const float* bias1  = (const float*)d_in[3];
  const float* comp2  = (const float*)d_in[4];
  const float* basis2 = (const float*)d_in[5];
  const float* root2  = (const float*)d_in[6];
  const float* bias2  = (const float*)d_in[7];
  const float* emb    = (const float*)d_in[8];
  const int*   ei     = (const int*)d_in[9];
  const int*   et     = (const int*)d_in[10];
  const int* srcp = ei;
  const int* dstp = ei + E_EDGES;

  float* xout = (float*)d_out;
  float* scratch = xout + NHTOT;            // 32M floats (overwritten by k_emb last)
  int*   cnt_nr = (int*)scratch;            // @0        400,000
  int*   deg    = cnt_nr + 400000;          // @400,000   10,000
  int*   rowptr = deg + 10000;              // @410,000   10,004
  int*   fill   = rowptr + 10004;           // @420,004   10,000
  int*   ebuf   = fill + 10000;             // @430,004  320,000 -> 750,004
  float* W2f    = scratch + 750016;         // 400,000 -> 1,150,016
  ushort* Bt    = (ushort*)(scratch + 1150016);  // 112*4224 bf16 = 236,544 f -> 1,386,560
  float* h      = scratch + 1386560;        // 1,000,000 -> 2,386,560
  uint*  W1bf   = (uint*)(scratch + 2386560);    // conv1 use: 20M floats
  uint*  hbar   = (uint*)(scratch + 2386560);    // conv2 use: 10048*2112 uints = 21.22M f
  float* part   = scratch + 23607936;       // 4*10048*112 = 4,501,504 -> 28,109,440 OK

  hipMemsetAsync(cnt_nr, 0, (size_t)430004 * sizeof(int), stream);
  // zero the 48 pad rows of hbar so GEMM tail reads zeros
  hipMemsetAsync((char*)hbar + (size_t)NN * KTOT * 2, 0,
                 (size_t)(NROWS_PAD - NN) * KTOT * 2, stream);

  k_count <<<(E_EDGES + 255) / 256, 256, 0, stream>>>(dstp, et, cnt_nr, deg);
  k_scan  <<<1, 256, 0, stream>>>(deg, rowptr);
  k_bucket<<<(E_EDGES + 255) / 256, 256, 0, stream>>>(srcp, dstp, et, rowptr, fill, ebuf);

  k_w2 <<<(HID * HID + 255) / 256, 256, 0, stream>>>(comp2, basis2, W2f);
  k_bt <<<(112 * KTOT + 255) / 256, 256, 0, stream>>>(W2f, root2, Bt);
  k_w1b<<<dim3((NHTOT / 2 + 255) / 256, RSPLIT), 256, 0, stream>>>(comp1, basis1, W1bf);

  k_agg1<<<NN, 256, 0, stream>>>(rowptr, ebuf, cnt_nr, W1bf, root1, bias1, h);
  k_hbar<<<NN, 512, 0, stream>>>(rowptr, ebuf, cnt_nr, h, hbar);
  k_gemm<<<dim3(NROWS_PAD / 64, SPLITK), 256, 0, stream>>>((const ushort*)hbar, Bt, part);
  k_red <<<(NHTOT + 255) / 256, 256, 0, stream>>>(part, bias2, xout);

  k_emb<<<(E_EDGES * 25 + 255) / 256, 256, 0, stream>>>((const float4*)emb, et,
                                                        (float4*)(xout + NHTOT));
}

// Round 9
// 329.450 us; speedup vs baseline: 1.2769x; 1.2769x over previous
//
#include <hip/hip_runtime.h>
#include <hip/hip_bf16.h>
#include <cstdint>
#include <cstddef>

#define E_EDGES 320000
#define NN 10000
#define NRELS 40
#define NB 30
#define HID 100
#define NHTOT (NN*HID)       // 1,000,000
#define R2 41                // 40 rels + root2 slot
#define KTOT 4224            // 41*100 = 4100 packed, padded to 33*128
#define NROWS_PAD 10048      // 157 blocks * 64 rows
#define SPLITK 4             // 132 kb-steps -> 33 per gy
#define KB_PER 33
#define RSPLIT 2
#define RPB (NRELS/RSPLIT)   // 20 rels per pass

typedef short bf16x8 __attribute__((ext_vector_type(8)));
typedef float f32x4 __attribute__((ext_vector_type(4)));
typedef float f32x2 __attribute__((ext_vector_type(2)));

__device__ inline ushort f2bf(float f) {
  uint x = __float_as_uint(f);
  return (ushort)((x + 0x7fffu + ((x >> 16) & 1u)) >> 16);
}
__device__ inline float bflo(uint u) { return __uint_as_float(u << 16); }
__device__ inline float bfhi(uint u) { return __uint_as_float(u & 0xffff0000u); }

__device__ inline void gload16(const void* g, void* l) {
  __builtin_amdgcn_global_load_lds(
      (const __attribute__((address_space(1))) void*)g,
      (__attribute__((address_space(3))) void*)l, 16, 0, 0);
}

// ---------------------------------------------------------------- edge meta
__global__ void k_count(const int* __restrict__ dst, const int* __restrict__ et,
                        int* __restrict__ cnt_nr, int* __restrict__ deg) {
  int e = blockIdx.x * blockDim.x + threadIdx.x;
  if (e >= E_EDGES) return;
  int d = dst[e], r = et[e];
  atomicAdd(&cnt_nr[d * NRELS + r], 1);
  atomicAdd(&deg[d], 1);
}

__global__ void k_scan(const int* __restrict__ deg, int* __restrict__ rowptr) {
  __shared__ int ssum[256];
  int t = threadIdx.x;
  const int per = (NN + 255) / 256;
  int base = t * per;
  int s = 0;
  for (int k = 0; k < per; ++k) { int i = base + k; if (i < NN) s += deg[i]; }
  ssum[t] = s; __syncthreads();
  for (int off = 1; off < 256; off <<= 1) {
    int v = (t >= off) ? ssum[t - off] : 0;
    __syncthreads();
    ssum[t] += v;
    __syncthreads();
  }
  int pre = (t == 0) ? 0 : ssum[t - 1];
  for (int k = 0; k < per; ++k) {
    int i = base + k;
    if (i < NN) { rowptr[i] = pre; pre += deg[i]; }
  }
  if (t == 255) rowptr[NN] = ssum[255];
}

// per-node exclusive scan of cnt_nr over rels -> pnr  (segment offsets)
__global__ void k_pnr(const int* __restrict__ cnt_nr, int* __restrict__ pnr) {
  int n = blockIdx.x * 256 + threadIdx.x;
  if (n >= NN) return;
  int s = 0;
  for (int r = 0; r < NRELS; ++r) {
    pnr[n * NRELS + r] = s;
    s += cnt_nr[n * NRELS + r];
  }
}

// bucket edges sorted by (dst, rel): segment-contiguous in ebuf
__global__ void k_bucket(const int* __restrict__ src, const int* __restrict__ dst,
                         const int* __restrict__ et, const int* __restrict__ rowptr,
                         const int* __restrict__ pnr, int* __restrict__ fill_nr,
                         int* __restrict__ ebuf) {
  int e = blockIdx.x * blockDim.x + threadIdx.x;
  if (e >= E_EDGES) return;
  int d = dst[e], r = et[e];
  int pos = rowptr[d] + pnr[d * NRELS + r] + atomicAdd(&fill_nr[d * NRELS + r], 1);
  ebuf[pos] = (src[e] << 6) | r;
}

// ---------------------------------------------------------------- W1 (bf16)
__global__ __launch_bounds__(256) void k_w1b(const float* __restrict__ comp1,
                                             const float* __restrict__ basis1,
                                             uint* __restrict__ W1bf) {
  __shared__ float sct[NB][RPB];   // comp1 chunk transposed: [b][r_local]
  int t = threadIdx.x;
  int rbase = blockIdx.y * RPB;
  for (int i = t; i < RPB * NB; i += 256) {
    int r = i / NB, b = i - r * NB;
    sct[b][r] = comp1[(rbase + r) * NB + b];
  }
  __syncthreads();
  int i2 = blockIdx.x * 256 + t;
  if (i2 >= NHTOT / 2) return;
  f32x2 acc[RPB];
#pragma unroll
  for (int r = 0; r < RPB; ++r) acc[r] = (f32x2){0.f, 0.f};
  for (int b = 0; b < NB; ++b) {
    f32x2 v = ((const f32x2*)basis1)[(size_t)b * (NHTOT / 2) + i2];
#pragma unroll
    for (int r4 = 0; r4 < RPB / 4; ++r4) {
      float4 c = *(const float4*)&sct[b][r4 * 4];   // broadcast ds_read_b128
      acc[r4*4+0] += (f32x2){c.x, c.x} * v;
      acc[r4*4+1] += (f32x2){c.y, c.y} * v;
      acc[r4*4+2] += (f32x2){c.z, c.z} * v;
      acc[r4*4+3] += (f32x2){c.w, c.w} * v;
    }
  }
#pragma unroll
  for (int r = 0; r < RPB; ++r)
    W1bf[(size_t)(rbase + r) * (NHTOT / 2) + i2] =
        (uint)f2bf(acc[r].x) | ((uint)f2bf(acc[r].y) << 16);
}

// ---------------------------------------------------------------- W2 fp32 then packed Bt bf16
__global__ void k_w2(const float* __restrict__ comp2, const float* __restrict__ basis2,
                     float* __restrict__ W2f) {
  int i = blockIdx.x * 256 + threadIdx.x;
  if (i >= HID * HID) return;
  float v[NB];
#pragma unroll
  for (int b = 0; b < NB; ++b) v[b] = basis2[b * HID * HID + i];
  for (int r = 0; r < NRELS; ++r) {
    float a = 0.f;
#pragma unroll
    for (int b = 0; b < NB; ++b) a += comp2[r * NB + b] * v[b];
    W2f[r * HID * HID + i] = a;
  }
}

// Bt[col][kk] packed K: kk = r*100 + k  (r<40: W2f[r][k][col], r==40: root2[k][col])
__global__ void k_bt(const float* __restrict__ W2f, const float* __restrict__ root2,
                     ushort* __restrict__ Bt) {
  int i = blockIdx.x * 256 + threadIdx.x;
  if (i >= 112 * KTOT) return;
  int col = i / KTOT, kk = i - col * KTOT;
  float v = 0.f;
  if (kk < R2 * HID && col < HID) {
    int r = kk / HID, k = kk - r * HID;
    v = (r < NRELS) ? W2f[(r * HID + k) * HID + col] : root2[k * HID + col];
  }
  Bt[i] = f2bf(v);
}

// ---------------------------------------------------------------- conv1 aggregate
// 5 edge-groups x 50 channel-threads; register partials + LDS reduce (no atomics).
__global__ __launch_bounds__(256) void k_agg1(const int* __restrict__ rowptr,
                                              const int* __restrict__ ebuf,
                                              const int* __restrict__ cnt_nr,
                                              const uint* __restrict__ W1bf,
                                              const float* __restrict__ root1,
                                              const float* __restrict__ bias1,
                                              float* __restrict__ h) {
  __shared__ float red[5][2][50];
  int n = blockIdx.x, t = threadIdx.x;
  int g = t / 50, c = t - g * 50;
  if (g < 5) {
    float a0 = 0.f, a1 = 0.f;
    int beg = rowptr[n], end = rowptr[n + 1];
    for (int j = beg + g; j < end; j += 5) {
      int pk = ebuf[j];
      int r = pk & 63, s = pk >> 6;
      float cf = 1.0f / (float)cnt_nr[n * NRELS + r];
      uint u = W1bf[(size_t)(r * NN + s) * 50 + c];
      a0 += cf * bflo(u);
      a1 += cf * bfhi(u);
    }
    red[g][0][c] = a0;
    red[g][1][c] = a1;
  }
  __syncthreads();
  if (t < 50) {
    float a0 = red[0][0][t] + red[1][0][t] + red[2][0][t] + red[3][0][t] + red[4][0][t];
    float a1 = red[0][1][t] + red[1][1][t] + red[2][1][t] + red[3][1][t] + red[4][1][t];
    int c0 = 2 * t, c1 = 2 * t + 1;
    float v0 = a0 + root1[n * HID + c0] + bias1[c0];
    float v1 = a1 + root1[n * HID + c1] + bias1[c1];
    h[n * HID + c0] = v0 > 0.f ? v0 : 0.f;
    h[n * HID + c1] = v1 > 0.f ? v1 : 0.f;
  }
}

// ---------------------------------------------------------------- hbar: segmented, wave-per-(n,r)
// Edges sorted by (dst,rel) -> each (n,r) is a contiguous ebuf run. One wave
// per task: 50 lanes hold the f32x2 channel pair in REGISTERS, loop cnt edges
// (avg 0.8), scale, pack bf16, store. No LDS, no atomics (r8 lesson: fp
// atomicAdd compiles to CAS loops in this harness -> 190us). r==40 task
// copies h row; idle lanes zero the 62-uint row tail.
__global__ __launch_bounds__(512) void k_hseg(const int* __restrict__ rowptr,
                                              const int* __restrict__ pnr,
                                              const int* __restrict__ cnt_nr,
                                              const int* __restrict__ ebuf,
                                              const float* __restrict__ h,
                                              uint* __restrict__ hbar) {
  int task = blockIdx.x * 8 + (threadIdx.x >> 6);
  if (task >= NN * R2) return;
  int n = task / R2, r = task - n * R2;
  int lane = threadIdx.x & 63;
  uint* orow = hbar + (size_t)n * (KTOT / 2);
  if (r == NRELS) {   // root slot: copy h[n]
    if (lane < 50) {
      f32x2 v = ((const f32x2*)h)[n * 50 + lane];
      orow[NRELS * 50 + lane] = (uint)f2bf(v.x) | ((uint)f2bf(v.y) << 16);
    }
    return;
  }
  int cnt = cnt_nr[n * NRELS + r];
  int beg = rowptr[n] + pnr[n * NRELS + r];
  f32x2 a = (f32x2){0.f, 0.f};
  for (int j = 0; j < cnt; ++j) {
    int s = ebuf[beg + j] >> 6;
    if (lane < 50) a += ((const f32x2*)h)[s * 50 + lane];
  }
  if (lane < 50) {
    float coef = cnt ? 1.0f / (float)cnt : 0.f;
    orow[r * 50 + lane] = (uint)f2bf(a.x * coef) | ((uint)f2bf(a.y * coef) << 16);
  } else {
    int idx = r * 14 + (lane - 50);
    if (idx < (KTOT / 2 - R2 * 50)) orow[R2 * 50 + idx] = 0;   // zero row tail
  }
}

// ---------------------------------------------------------------- split-K MFMA GEMM
// 2-phase double-buffered LDS pipeline (guide §5.5 T3-minimum).
__global__ __launch_bounds__(256) void k_gemm(const ushort* __restrict__ hbar,
                                              const ushort* __restrict__ Bt,
                                              float* __restrict__ part) {
  __shared__ char lds[2][12288];
  int t = threadIdx.x;
  int wid = t >> 6, l = t & 63;
  int lrow = l & 15, g16 = l >> 4;
  int kb0 = blockIdx.y * KB_PER;
  int row0 = blockIdx.x * 64;

  f32x4 acc[7];
#pragma unroll
  for (int j = 0; j < 7; ++j) acc[j] = (f32x4){0.f, 0.f, 0.f, 0.f};

  auto stage = [&](int p, int buf) {
    int kbg = kb0 + p;
#pragma unroll
    for (int ci = 0; ci < 3; ++ci) {
      int qb = (wid * 3 + ci) * 64;
      int q = qb + l;
      const ushort* g;
      if (q < 448) {                       // B chunk
        int col = q >> 2, c = q & 3;
        g = Bt + (size_t)col * KTOT + kbg * 32 + c * 8;
      } else if (q < 704) {                // A chunk
        int qq = q - 448;
        int row = qq >> 2, c = qq & 3;
        g = hbar + (size_t)(row0 + row) * KTOT + kbg * 32 + c * 8;
      } else {                             // pad
        g = Bt;
      }
      gload16(g, &lds[buf][(size_t)qb * 16]);
    }
  };

  stage(0, 0);
  __syncthreads();

  int cur = 0;
  for (int p = 0; p < KB_PER; ++p) {
    if (p + 1 < KB_PER) stage(p + 1, cur ^ 1);
    const char* base = lds[cur];
    bf16x8 a = *(const bf16x8*)(base + 7168 + (wid * 16 + lrow) * 64 + g16 * 16);
#pragma unroll
    for (int j = 0; j < 7; ++j) {
      bf16x8 b = *(const bf16x8*)(base + (j * 16 + lrow) * 64 + g16 * 16);
      acc[j] = __builtin_amdgcn_mfma_f32_16x16x32_bf16(a, b, acc[j], 0, 0, 0);
    }
    __syncthreads();
    cur ^= 1;
  }

  float* pp = part + (size_t)blockIdx.y * NROWS_PAD * 112;
  int srow = row0 + wid * 16 + g16 * 4;
#pragma unroll
  for (int j = 0; j < 7; ++j) {
    int col = j * 16 + lrow;
#pragma unroll
    for (int v = 0; v < 4; ++v)
      pp[(size_t)(srow + v) * 112 + col] = acc[j][v];
  }
}

// reduce partials + bias
__global__ void k_red(const float* __restrict__ part, const float* __restrict__ bias2,
                      float* __restrict__ xout) {
  int i = blockIdx.x * 256 + threadIdx.x;
  if (i >= NHTOT) return;
  int n = i / HID, c = i - n * HID;
  float s = bias2[c];
#pragma unroll
  for (int g = 0; g < SPLITK; ++g)
    s += part[(size_t)g * NROWS_PAD * 112 + (size_t)n * 112 + c];
  xout[i] = s;
}

// ---------------------------------------------------------------- rel_embedded
__global__ void k_emb(const float4* __restrict__ emb, const int* __restrict__ et,
                      float4* __restrict__ out2) {
  int i = blockIdx.x * 256 + threadIdx.x;
  if (i >= E_EDGES * 25) return;
  int e = i / 25, q = i - e * 25;
  int r = et[e];
  float4 v;
  if (r == 0) { v.x = 0.f; v.y = 0.f; v.z = 0.f; v.w = 0.f; }
  else v = emb[r * 25 + q];
  out2[i] = v;
}

// ---------------------------------------------------------------- launch
extern "C" void kernel_launch(void* const* d_in, const int* in_sizes, int n_in,
                              void* d_out, int out_size, void* d_ws, size_t ws_size,
                              hipStream_t stream) {
  (void)in_sizes; (void)n_in; (void)out_size; (void)d_ws; (void)ws_size;

  const float* comp1  = (const float*)d_in[0];
  const float* basis1 = (const float*)d_in[1];
  const float* root1  = (const float*)d_in[2];
  const float* bias1  = (const float*)d_in[3];
  const float* comp2  = (const float*)d_in[4];
  const float* basis2 = (const float*)d_in[5];
  const float* root2  = (const float*)d_in[6];
  const float* bias2  = (const float*)d_in[7];
  const float* emb    = (const float*)d_in[8];
  const int*   ei     = (const int*)d_in[9];
  const int*   et     = (const int*)d_in[10];
  const int* srcp = ei;
  const int* dstp = ei + E_EDGES;

  float* xout = (float*)d_out;
  float* scratch = xout + NHTOT;            // 32M floats (overwritten by k_emb last)
  int*   cnt_nr = (int*)scratch;            // @0          400,000
  int*   deg    = cnt_nr + 400000;          // @400,000     10,000
  int*   rowptr = deg + 10000;              // @410,000     10,004
  int*   pnr    = rowptr + 10004;           // @420,004    400,000
  int*   fill_nr= pnr + 400000;             // @820,004    400,000
  int*   ebuf   = fill_nr + 400000;         // @1,220,004  320,000 -> 1,540,004
  float* W2f    = scratch + 1540016;        // 400,000 -> 1,940,016
  ushort* Bt    = (ushort*)(scratch + 1940016);  // 236,544 f -> 2,176,560
  float* h      = scratch + 2176560;        // 1,000,000 -> 3,176,560
  uint*  W1bf   = (uint*)(scratch + 3176576);    // conv1 use: 20M
  uint*  hbar   = (uint*)(scratch + 3176576);    // conv2 use: 10048*2112 = 21,221,376 -> 24,397,952
  float* part   = scratch + 24397952;       // 4*10048*112 = 4,501,504 -> 28,899,456 < 32M OK

  // zero cnt_nr/deg/rowptr/pnr/fill_nr in one shot (ebuf fully overwritten)
  hipMemsetAsync(cnt_nr, 0, (size_t)1220004 * sizeof(int), stream);
  // zero the 48 pad rows of hbar so GEMM tail reads zeros
  hipMemsetAsync((char*)hbar + (size_t)NN * KTOT * 2, 0,
                 (size_t)(NROWS_PAD - NN) * KTOT * 2, stream);

  k_count <<<(E_EDGES + 255) / 256, 256, 0, stream>>>(dstp, et, cnt_nr, deg);
  k_scan  <<<1, 256, 0, stream>>>(deg, rowptr);
  k_pnr   <<<(NN + 255) / 256, 256, 0, stream>>>(cnt_nr, pnr);
  k_bucket<<<(E_EDGES + 255) / 256, 256, 0, stream>>>(srcp, dstp, et, rowptr, pnr,
                                                      fill_nr, ebuf);

  k_w2 <<<(HID * HID + 255) / 256, 256, 0, stream>>>(comp2, basis2, W2f);
  k_bt <<<(112 * KTOT + 255) / 256, 256, 0, stream>>>(W2f, root2, Bt);
  k_w1b<<<dim3((NHTOT / 2 + 255) / 256, RSPLIT), 256, 0, stream>>>(comp1, basis1, W1bf);

  k_agg1<<<NN, 256, 0, stream>>>(rowptr, ebuf, cnt_nr, W1bf, root1, bias1, h);
  k_hseg<<<(NN * R2 + 7) / 8, 512, 0, stream>>>(rowptr, pnr, cnt_nr, ebuf, h, hbar);
  k_gemm<<<dim3(NROWS_PAD / 64, SPLITK), 256, 0, stream>>>((const ushort*)hbar, Bt, part);
  k_red <<<(NHTOT + 255) / 256, 256, 0, stream>>>(part, bias2, xout);

  k_emb<<<(E_EDGES * 25 + 255) / 256, 256, 0, stream>>>((const float4*)emb, et,
                                                        (float4*)(xout + NHTOT));
}

// Round 11
// 318.063 us; speedup vs baseline: 1.3226x; 1.0358x over previous
//
#include <hip/hip_runtime.h>
#include <hip/hip_bf16.h>
#include <cstdint>
#include <cstddef>

#define E_EDGES 320000
#define NN 10000
#define NRELS 40
#define NB 30
#define HID 100
#define NHTOT (NN*HID)       // 1,000,000
#define R2 41                // 40 rels + root2 slot
#define KTOT 4224            // 41*100 = 4100 packed, padded to 33*128
#define NROWS_PAD 10048      // 157 blocks * 64 rows
#define SPLITK 4             // 132 kb-steps -> 33 per gy
#define KB_PER 33
#define RSPLIT 2
#define RPB (NRELS/RSPLIT)   // 20 rels per pass

typedef short bf16x8 __attribute__((ext_vector_type(8)));
typedef float f32x4 __attribute__((ext_vector_type(4)));
typedef float f32x2 __attribute__((ext_vector_type(2)));

__device__ inline ushort f2bf(float f) {
  uint x = __float_as_uint(f);
  return (ushort)((x + 0x7fffu + ((x >> 16) & 1u)) >> 16);
}
__device__ inline float bflo(uint u) { return __uint_as_float(u << 16); }
__device__ inline float bfhi(uint u) { return __uint_as_float(u & 0xffff0000u); }

__device__ inline void gload16(const void* g, void* l) {
  __builtin_amdgcn_global_load_lds(
      (const __attribute__((address_space(1))) void*)g,
      (__attribute__((address_space(3))) void*)l, 16, 0, 0);
}

// ---------------------------------------------------------------- edge meta
__global__ void k_count(const int* __restrict__ dst, const int* __restrict__ et,
                        int* __restrict__ cnt_nr, int* __restrict__ deg) {
  int e = blockIdx.x * blockDim.x + threadIdx.x;
  if (e >= E_EDGES) return;
  int d = dst[e], r = et[e];
  atomicAdd(&cnt_nr[d * NRELS + r], 1);
  atomicAdd(&deg[d], 1);
}

__global__ void k_scan(const int* __restrict__ deg, int* __restrict__ rowptr) {
  __shared__ int ssum[256];
  int t = threadIdx.x;
  const int per = (NN + 255) / 256;
  int base = t * per;
  int s = 0;
  for (int k = 0; k < per; ++k) { int i = base + k; if (i < NN) s += deg[i]; }
  ssum[t] = s; __syncthreads();
  for (int off = 1; off < 256; off <<= 1) {
    int v = (t >= off) ? ssum[t - off] : 0;
    __syncthreads();
    ssum[t] += v;
    __syncthreads();
  }
  int pre = (t == 0) ? 0 : ssum[t - 1];
  for (int k = 0; k < per; ++k) {
    int i = base + k;
    if (i < NN) { rowptr[i] = pre; pre += deg[i]; }
  }
  if (t == 255) rowptr[NN] = ssum[255];
}

// per-node scan over rels -> task descriptors desc[n*40+r] = {segment begin, cnt}
__global__ void k_pnr(const int* __restrict__ cnt_nr, const int* __restrict__ rowptr,
                      int2* __restrict__ desc) {
  int n = blockIdx.x * 256 + threadIdx.x;
  if (n >= NN) return;
  int s = rowptr[n];
  for (int r = 0; r < NRELS; ++r) {
    int c = cnt_nr[n * NRELS + r];
    desc[n * NRELS + r] = make_int2(s, c);
    s += c;
  }
}

// bucket edges sorted by (dst, rel): segment-contiguous in ebuf
__global__ void k_bucket(const int* __restrict__ src, const int* __restrict__ dst,
                         const int* __restrict__ et, const int2* __restrict__ desc,
                         int* __restrict__ fill_nr, int* __restrict__ ebuf) {
  int e = blockIdx.x * blockDim.x + threadIdx.x;
  if (e >= E_EDGES) return;
  int d = dst[e], r = et[e];
  int pos = desc[d * NRELS + r].x + atomicAdd(&fill_nr[d * NRELS + r], 1);
  ebuf[pos] = (src[e] << 6) | r;
}

// ---------------------------------------------------------------- W1 (bf16)
__global__ __launch_bounds__(256) void k_w1b(const float* __restrict__ comp1,
                                             const float* __restrict__ basis1,
                                             uint* __restrict__ W1bf) {
  __shared__ float sct[NB][RPB];   // comp1 chunk transposed: [b][r_local]
  int t = threadIdx.x;
  int rbase = blockIdx.y * RPB;
  for (int i = t; i < RPB * NB; i += 256) {
    int r = i / NB, b = i - r * NB;
    sct[b][r] = comp1[(rbase + r) * NB + b];
  }
  __syncthreads();
  int i2 = blockIdx.x * 256 + t;
  if (i2 >= NHTOT / 2) return;
  f32x2 acc[RPB];
#pragma unroll
  for (int r = 0; r < RPB; ++r) acc[r] = (f32x2){0.f, 0.f};
  for (int b = 0; b < NB; ++b) {
    f32x2 v = ((const f32x2*)basis1)[(size_t)b * (NHTOT / 2) + i2];
#pragma unroll
    for (int r4 = 0; r4 < RPB / 4; ++r4) {
      float4 c = *(const float4*)&sct[b][r4 * 4];   // broadcast ds_read_b128
      acc[r4*4+0] += (f32x2){c.x, c.x} * v;
      acc[r4*4+1] += (f32x2){c.y, c.y} * v;
      acc[r4*4+2] += (f32x2){c.z, c.z} * v;
      acc[r4*4+3] += (f32x2){c.w, c.w} * v;
    }
  }
#pragma unroll
  for (int r = 0; r < RPB; ++r)
    W1bf[(size_t)(rbase + r) * (NHTOT / 2) + i2] =
        (uint)f2bf(acc[r].x) | ((uint)f2bf(acc[r].y) << 16);
}

// ---------------------------------------------------------------- W2 fp32 then packed Bt bf16
__global__ void k_w2(const float* __restrict__ comp2, const float* __restrict__ basis2,
                     float* __restrict__ W2f) {
  int i = blockIdx.x * 256 + threadIdx.x;
  if (i >= HID * HID) return;
  float v[NB];
#pragma unroll
  for (int b = 0; b < NB; ++b) v[b] = basis2[b * HID * HID + i];
  for (int r = 0; r < NRELS; ++r) {
    float a = 0.f;
#pragma unroll
    for (int b = 0; b < NB; ++b) a += comp2[r * NB + b] * v[b];
    W2f[r * HID * HID + i] = a;
  }
}

// Bt[col][kk] packed K: kk = r*100 + k  (r<40: W2f[r][k][col], r==40: root2[k][col])
__global__ void k_bt(const float* __restrict__ W2f, const float* __restrict__ root2,
                     ushort* __restrict__ Bt) {
  int i = blockIdx.x * 256 + threadIdx.x;
  if (i >= 112 * KTOT) return;
  int col = i / KTOT, kk = i - col * KTOT;
  float v = 0.f;
  if (kk < R2 * HID && col < HID) {
    int r = kk / HID, k = kk - r * HID;
    v = (r < NRELS) ? W2f[(r * HID + k) * HID + col] : root2[k * HID + col];
  }
  Bt[i] = f2bf(v);
}

// ---------------------------------------------------------------- conv1 aggregate
// 10 edge-groups x 25 channel-lanes (uint2 = 4 bf16 per load); LDS reduce.
__global__ __launch_bounds__(256) void k_agg1(const int* __restrict__ rowptr,
                                              const int* __restrict__ ebuf,
                                              const int* __restrict__ cnt_nr,
                                              const uint2* __restrict__ W1bf2,
                                              const float4* __restrict__ root1,
                                              const float4* __restrict__ bias1,
                                              float4* __restrict__ h4) {
  __shared__ f32x4 red[10][25];
  int n = blockIdx.x, t = threadIdx.x;
  int g = t / 25, c = t - g * 25;
  if (g < 10) {
    f32x4 a = (f32x4){0.f, 0.f, 0.f, 0.f};
    int beg = rowptr[n], end = rowptr[n + 1];
    for (int j = beg + g; j < end; j += 10) {
      int pk = ebuf[j];
      int r = pk & 63, s = pk >> 6;
      float cf = 1.0f / (float)cnt_nr[n * NRELS + r];
      uint2 u = W1bf2[(size_t)r * 250000 + s * 25 + c];
      a[0] += cf * bflo(u.x); a[1] += cf * bfhi(u.x);
      a[2] += cf * bflo(u.y); a[3] += cf * bfhi(u.y);
    }
    red[g][c] = a;
  }
  __syncthreads();
  if (t < 25) {
    f32x4 a = red[0][t];
#pragma unroll
    for (int g2 = 1; g2 < 10; ++g2) a += red[g2][t];
    float4 rt = root1[n * 25 + t];
    float4 bs = bias1[t];
    a += (f32x4){rt.x, rt.y, rt.z, rt.w};
    a += (f32x4){bs.x, bs.y, bs.z, bs.w};
#pragma unroll
    for (int q = 0; q < 4; ++q) if (a[q] < 0.f) a[q] = 0.f;
    h4[n * 25 + t] = make_float4(a[0], a[1], a[2], a[3]);
  }
}

// ---------------------------------------------------------------- hbar: segmented, wave-per-(n,r)
// desc collapses the address chain to desc -> ebuf -> h (was rowptr/pnr/cnt ->
// ebuf -> h). 25 lanes x float4 per h row; cnt==0 (~45% of segments) is
// desc->store only. No fp atomics (r8: shared-fp atomicAdd = CAS loop).
__global__ __launch_bounds__(512) void k_hseg(const int2* __restrict__ desc,
                                              const int* __restrict__ ebuf,
                                              const f32x4* __restrict__ h4,
                                              uint2* __restrict__ hbar2) {
  int task = blockIdx.x * 8 + (threadIdx.x >> 6);
  if (task >= NN * R2) return;
  int n = task / R2, r = task - n * R2;
  int lane = threadIdx.x & 63;
  uint2* orow = hbar2 + (size_t)n * (KTOT / 4);   // 1056 uint2 per row
  if (r == NRELS) {   // root slot: copy h[n]
    if (lane < 25) {
      f32x4 v = h4[n * 25 + lane];
      orow[NRELS * 25 + lane] =
          make_uint2((uint)f2bf(v[0]) | ((uint)f2bf(v[1]) << 16),
                     (uint)f2bf(v[2]) | ((uint)f2bf(v[3]) << 16));
    }
    return;
  }
  int2 d = desc[n * NRELS + r];
  if (lane < 25) {
    f32x4 a = (f32x4){0.f, 0.f, 0.f, 0.f};
    for (int j = 0; j < d.y; ++j) {
      int s = ebuf[d.x + j] >> 6;
      a += h4[s * 25 + lane];
    }
    float coef = d.y ? 1.0f / (float)d.y : 0.f;
    a *= coef;
    orow[r * 25 + lane] =
        make_uint2((uint)f2bf(a[0]) | ((uint)f2bf(a[1]) << 16),
                   (uint)f2bf(a[2]) | ((uint)f2bf(a[3]) << 16));
  } else if (lane == 32 && r < 31) {
    orow[R2 * 25 + r] = make_uint2(0u, 0u);   // zero the 31-uint2 row tail
  }
}

// ---------------------------------------------------------------- split-K MFMA GEMM
// 2-phase double-buffered LDS pipeline (guide §5.5 T3-minimum).
__global__ __launch_bounds__(256) void k_gemm(const ushort* __restrict__ hbar,
                                              const ushort* __restrict__ Bt,
                                              float* __restrict__ part) {
  __shared__ char lds[2][12288];
  int t = threadIdx.x;
  int wid = t >> 6, l = t & 63;
  int lrow = l & 15, g16 = l >> 4;
  int kb0 = blockIdx.y * KB_PER;
  int row0 = blockIdx.x * 64;

  f32x4 acc[7];
#pragma unroll
  for (int j = 0; j < 7; ++j) acc[j] = (f32x4){0.f, 0.f, 0.f, 0.f};

  auto stage = [&](int p, int buf) {
    int kbg = kb0 + p;
#pragma unroll
    for (int ci = 0; ci < 3; ++ci) {
      int qb = (wid * 3 + ci) * 64;
      int q = qb + l;
      const ushort* g;
      if (q < 448) {                       // B chunk
        int col = q >> 2, c = q & 3;
        g = Bt + (size_t)col * KTOT + kbg * 32 + c * 8;
      } else if (q < 704) {                // A chunk
        int qq = q - 448;
        int row = qq >> 2, c = qq & 3;
        g = hbar + (size_t)(row0 + row) * KTOT + kbg * 32 + c * 8;
      } else {                             // pad
        g = Bt;
      }
      gload16(g, &lds[buf][(size_t)qb * 16]);
    }
  };

  stage(0, 0);
  __syncthreads();

  int cur = 0;
  for (int p = 0; p < KB_PER; ++p) {
    if (p + 1 < KB_PER) stage(p + 1, cur ^ 1);
    const char* base = lds[cur];
    bf16x8 a = *(const bf16x8*)(base + 7168 + (wid * 16 + lrow) * 64 + g16 * 16);
#pragma unroll
    for (int j = 0; j < 7; ++j) {
      bf16x8 b = *(const bf16x8*)(base + (j * 16 + lrow) * 64 + g16 * 16);
      acc[j] = __builtin_amdgcn_mfma_f32_16x16x32_bf16(a, b, acc[j], 0, 0, 0);
    }
    __syncthreads();
    cur ^= 1;
  }

  float* pp = part + (size_t)blockIdx.y * NROWS_PAD * 112;
  int srow = row0 + wid * 16 + g16 * 4;
#pragma unroll
  for (int j = 0; j < 7; ++j) {
    int col = j * 16 + lrow;
#pragma unroll
    for (int v = 0; v < 4; ++v)
      pp[(size_t)(srow + v) * 112 + col] = acc[j][v];
  }
}

// reduce partials + bias
__global__ void k_red(const float* __restrict__ part, const float* __restrict__ bias2,
                      float* __restrict__ xout) {
  int i = blockIdx.x * 256 + threadIdx.x;
  if (i >= NHTOT) return;
  int n = i / HID, c = i - n * HID;
  float s = bias2[c];
#pragma unroll
  for (int g = 0; g < SPLITK; ++g)
    s += part[(size_t)g * NROWS_PAD * 112 + (size_t)n * 112 + c];
  xout[i] = s;
}

// ---------------------------------------------------------------- rel_embedded
__global__ void k_emb(const float4* __restrict__ emb, const int* __restrict__ et,
                      float4* __restrict__ out2) {
  int i = blockIdx.x * 256 + threadIdx.x;
  if (i >= E_EDGES * 25) return;
  int e = i / 25, q = i - e * 25;
  int r = et[e];
  float4 v;
  if (r == 0) { v.x = 0.f; v.y = 0.f; v.z = 0.f; v.w = 0.f; }
  else v = emb[r * 25 + q];
  out2[i] = v;
}

// ---------------------------------------------------------------- launch
extern "C" void kernel_launch(void* const* d_in, const int* in_sizes, int n_in,
                              void* d_out, int out_size, void* d_ws, size_t ws_size,
                              hipStream_t stream) {
  (void)in_sizes; (void)n_in; (void)out_size; (void)d_ws; (void)ws_size;

  const float* comp1  = (const float*)d_in[0];
  const float* basis1 = (const float*)d_in[1];
  const float* root1  = (const float*)d_in[2];
  const float* bias1  = (const float*)d_in[3];
  const float* comp2  = (const float*)d_in[4];
  const float* basis2 = (const float*)d_in[5];
  const float* root2  = (const float*)d_in[6];
  const float* bias2  = (const float*)d_in[7];
  const float* emb    = (const float*)d_in[8];
  const int*   ei     = (const int*)d_in[9];
  const int*   et     = (const int*)d_in[10];
  const int* srcp = ei;
  const int* dstp = ei + E_EDGES;

  float* xout = (float*)d_out;
  float* scratch = xout + NHTOT;            // 32M floats (overwritten by k_emb last)
  int*   cnt_nr = (int*)scratch;            // @0          400,000
  int*   deg    = cnt_nr + 400000;          // @400,000     10,000
  int*   rowptr = deg + 10000;              // @410,000     10,004
  int*   fill_nr= rowptr + 10004;           // @420,004    400,000
  int2*  desc   = (int2*)(scratch + 820004);// @820,004    800,000 ints (even: 8B ok)
  int*   ebuf   = (int*)(scratch + 1620004);// @1,620,004  320,000 -> 1,940,004
  float* W2f    = scratch + 1940016;        // 400,000 -> 2,340,016
  ushort* Bt    = (ushort*)(scratch + 2340016);  // 236,544 f -> 2,576,560
  float* h      = scratch + 2576560;        // 1,000,000 -> 3,576,560
  uint*  W1bf   = (uint*)(scratch + 3576560);    // conv1 use: 20M
  uint*  hbar   = (uint*)(scratch + 3576560);    // conv2 use: 21,221,376 -> 24,797,936
  float* part   = scratch + 24797936;       // 4*10048*112 = 4,501,504 -> 29,299,440 OK

  // zero cnt_nr / deg / fill_nr (rowptr, desc, ebuf fully written)
  hipMemsetAsync(cnt_nr, 0, (size_t)820004 * sizeof(int), stream);
  // zero the 48 pad rows of hbar so GEMM tail reads zeros
  hipMemsetAsync((char*)hbar + (size_t)NN * KTOT * 2, 0,
                 (size_t)(NROWS_PAD - NN) * KTOT * 2, stream);

  k_count <<<(E_EDGES + 255) / 256, 256, 0, stream>>>(dstp, et, cnt_nr, deg);
  k_scan  <<<1, 256, 0, stream>>>(deg, rowptr);
  k_pnr   <<<(NN + 255) / 256, 256, 0, stream>>>(cnt_nr, rowptr, desc);
  k_bucket<<<(E_EDGES + 255) / 256, 256, 0, stream>>>(srcp, dstp, et, desc,
                                                      fill_nr, ebuf);

  k_w2 <<<(HID * HID + 255) / 256, 256, 0, stream>>>(comp2, basis2, W2f);
  k_bt <<<(112 * KTOT + 255) / 256, 256, 0, stream>>>(W2f, root2, Bt);
  k_w1b<<<dim3((NHTOT / 2 + 255) / 256, RSPLIT), 256, 0, stream>>>(comp1, basis1, W1bf);

  k_agg1<<<NN, 256, 0, stream>>>(rowptr, ebuf, cnt_nr, (const uint2*)W1bf,
                                 (const float4*)root1, (const float4*)bias1,
                                 (float4*)h);
  k_hseg<<<(NN * R2 + 7) / 8, 512, 0, stream>>>(desc, ebuf, (const f32x4*)h,
                                                (uint2*)hbar);
  k_gemm<<<dim3(NROWS_PAD / 64, SPLITK), 256, 0, stream>>>((const ushort*)hbar, Bt, part);
  k_red <<<(NHTOT + 255) / 256, 256, 0, stream>>>(part, bias2, xout);

  k_emb<<<(E_EDGES * 25 + 255) / 256, 256, 0, stream>>>((const float4*)emb, et,
                                                        (float4*)(xout + NHTOT));
}

// Round 12
// 283.209 us; speedup vs baseline: 1.4854x; 1.1231x over previous
//
#include <hip/hip_runtime.h>
#include <hip/hip_bf16.h>
#include <cstdint>
#include <cstddef>

#define E_EDGES 320000
#define NN 10000
#define NRELS 40
#define NB 30
#define HID 100
#define NHTOT (NN*HID)       // 1,000,000
#define R2 41                // 40 rels + root2 slot
#define KTOT 4224            // 41*100 = 4100 packed, padded to 33*128
#define NROWS_PAD 10048      // 157 blocks * 64 rows
#define SPLITK 4             // 132 kb-steps -> 33 per gy
#define KB_PER 33
#define RSPLIT 2
#define RPB (NRELS/RSPLIT)   // 20 rels per pass

typedef short bf16x8 __attribute__((ext_vector_type(8)));
typedef float f32x4 __attribute__((ext_vector_type(4)));
typedef float f32x2 __attribute__((ext_vector_type(2)));

__device__ inline ushort f2bf(float f) {
  uint x = __float_as_uint(f);
  return (ushort)((x + 0x7fffu + ((x >> 16) & 1u)) >> 16);
}
__device__ inline float bflo(uint u) { return __uint_as_float(u << 16); }
__device__ inline float bfhi(uint u) { return __uint_as_float(u & 0xffff0000u); }

// HW packed f32->bf16 RNE (v_cvt_pk_bf16_f32 via compiler; guide T12/m240:
// use the cast form, not inline asm)
__device__ inline uint pack2bf(float x, float y) {
  union { __hip_bfloat162 b; uint u; } cv;
  cv.b = __float22bfloat162_rn(make_float2(x, y));
  return cv.u;
}

__device__ inline void gload16(const void* g, void* l) {
  __builtin_amdgcn_global_load_lds(
      (const __attribute__((address_space(1))) void*)g,
      (__attribute__((address_space(3))) void*)l, 16, 0, 0);
}

// ---------------------------------------------------------------- edge meta
__global__ void k_count(const int* __restrict__ dst, const int* __restrict__ et,
                        int* __restrict__ cnt_nr, int* __restrict__ deg) {
  int e = blockIdx.x * blockDim.x + threadIdx.x;
  if (e >= E_EDGES) return;
  int d = dst[e], r = et[e];
  atomicAdd(&cnt_nr[d * NRELS + r], 1);
  atomicAdd(&deg[d], 1);
}

__global__ void k_scan(const int* __restrict__ deg, int* __restrict__ rowptr) {
  __shared__ int ssum[256];
  int t = threadIdx.x;
  const int per = (NN + 255) / 256;
  int base = t * per;
  int s = 0;
  for (int k = 0; k < per; ++k) { int i = base + k; if (i < NN) s += deg[i]; }
  ssum[t] = s; __syncthreads();
  for (int off = 1; off < 256; off <<= 1) {
    int v = (t >= off) ? ssum[t - off] : 0;
    __syncthreads();
    ssum[t] += v;
    __syncthreads();
  }
  int pre = (t == 0) ? 0 : ssum[t - 1];
  for (int k = 0; k < per; ++k) {
    int i = base + k;
    if (i < NN) { rowptr[i] = pre; pre += deg[i]; }
  }
  if (t == 255) rowptr[NN] = ssum[255];
}

// per-node scan over rels -> task descriptors desc[n*40+r] = {segment begin, cnt}
__global__ void k_pnr(const int* __restrict__ cnt_nr, const int* __restrict__ rowptr,
                      int2* __restrict__ desc) {
  int n = blockIdx.x * 256 + threadIdx.x;
  if (n >= NN) return;
  int s = rowptr[n];
  for (int r = 0; r < NRELS; ++r) {
    int c = cnt_nr[n * NRELS + r];
    desc[n * NRELS + r] = make_int2(s, c);
    s += c;
  }
}

// bucket edges sorted by (dst, rel): segment-contiguous in ebuf
__global__ void k_bucket(const int* __restrict__ src, const int* __restrict__ dst,
                         const int* __restrict__ et, const int2* __restrict__ desc,
                         int* __restrict__ fill_nr, int* __restrict__ ebuf) {
  int e = blockIdx.x * blockDim.x + threadIdx.x;
  if (e >= E_EDGES) return;
  int d = dst[e], r = et[e];
  int pos = desc[d * NRELS + r].x + atomicAdd(&fill_nr[d * NRELS + r], 1);
  ebuf[pos] = (src[e] << 6) | r;
}

// ---------------------------------------------------------------- W1 (bf16)
__global__ __launch_bounds__(256) void k_w1b(const float* __restrict__ comp1,
                                             const float* __restrict__ basis1,
                                             uint* __restrict__ W1bf) {
  __shared__ float sct[NB][RPB];   // comp1 chunk transposed: [b][r_local]
  int t = threadIdx.x;
  int rbase = blockIdx.y * RPB;
  for (int i = t; i < RPB * NB; i += 256) {
    int r = i / NB, b = i - r * NB;
    sct[b][r] = comp1[(rbase + r) * NB + b];
  }
  __syncthreads();
  int i2 = blockIdx.x * 256 + t;
  if (i2 >= NHTOT / 2) return;
  f32x2 acc[RPB];
#pragma unroll
  for (int r = 0; r < RPB; ++r) acc[r] = (f32x2){0.f, 0.f};
  for (int b = 0; b < NB; ++b) {
    f32x2 v = ((const f32x2*)basis1)[(size_t)b * (NHTOT / 2) + i2];
#pragma unroll
    for (int r4 = 0; r4 < RPB / 4; ++r4) {
      float4 c = *(const float4*)&sct[b][r4 * 4];   // broadcast ds_read_b128
      acc[r4*4+0] += (f32x2){c.x, c.x} * v;
      acc[r4*4+1] += (f32x2){c.y, c.y} * v;
      acc[r4*4+2] += (f32x2){c.z, c.z} * v;
      acc[r4*4+3] += (f32x2){c.w, c.w} * v;
    }
  }
#pragma unroll
  for (int r = 0; r < RPB; ++r)
    W1bf[(size_t)(rbase + r) * (NHTOT / 2) + i2] = pack2bf(acc[r].x, acc[r].y);
}

// ---------------------------------------------------------------- W2 fp32 then packed Bt bf16
__global__ void k_w2(const float* __restrict__ comp2, const float* __restrict__ basis2,
                     float* __restrict__ W2f) {
  int i = blockIdx.x * 256 + threadIdx.x;
  if (i >= HID * HID) return;
  float v[NB];
#pragma unroll
  for (int b = 0; b < NB; ++b) v[b] = basis2[b * HID * HID + i];
  for (int r = 0; r < NRELS; ++r) {
    float a = 0.f;
#pragma unroll
    for (int b = 0; b < NB; ++b) a += comp2[r * NB + b] * v[b];
    W2f[r * HID * HID + i] = a;
  }
}

// Bt[col][kk] packed K: kk = r*100 + k  (r<40: W2f[r][k][col], r==40: root2[k][col])
__global__ void k_bt(const float* __restrict__ W2f, const float* __restrict__ root2,
                     ushort* __restrict__ Bt) {
  int i = blockIdx.x * 256 + threadIdx.x;
  if (i >= 112 * KTOT) return;
  int col = i / KTOT, kk = i - col * KTOT;
  float v = 0.f;
  if (kk < R2 * HID && col < HID) {
    int r = kk / HID, k = kk - r * HID;
    v = (r < NRELS) ? W2f[(r * HID + k) * HID + col] : root2[k * HID + col];
  }
  Bt[i] = f2bf(v);
}

// ---------------------------------------------------------------- conv1 aggregate
// 10 edge-groups x 25 channel-lanes (uint2 = 4 bf16 per load); LDS reduce.
__global__ __launch_bounds__(256) void k_agg1(const int* __restrict__ rowptr,
                                              const int* __restrict__ ebuf,
                                              const int* __restrict__ cnt_nr,
                                              const uint2* __restrict__ W1bf2,
                                              const float4* __restrict__ root1,
                                              const float4* __restrict__ bias1,
                                              float4* __restrict__ h4) {
  __shared__ f32x4 red[10][25];
  int n = blockIdx.x, t = threadIdx.x;
  int g = t / 25, c = t - g * 25;
  if (g < 10) {
    f32x4 a = (f32x4){0.f, 0.f, 0.f, 0.f};
    int beg = rowptr[n], end = rowptr[n + 1];
    for (int j = beg + g; j < end; j += 10) {
      int pk = ebuf[j];
      int r = pk & 63, s = pk >> 6;
      float cf = 1.0f / (float)cnt_nr[n * NRELS + r];
      uint2 u = W1bf2[(size_t)r * 250000 + s * 25 + c];
      a[0] += cf * bflo(u.x); a[1] += cf * bfhi(u.x);
      a[2] += cf * bflo(u.y); a[3] += cf * bfhi(u.y);
    }
    red[g][c] = a;
  }
  __syncthreads();
  if (t < 25) {
    f32x4 a = red[0][t];
#pragma unroll
    for (int g2 = 1; g2 < 10; ++g2) a += red[g2][t];
    float4 rt = root1[n * 25 + t];
    float4 bs = bias1[t];
    a += (f32x4){rt.x, rt.y, rt.z, rt.w};
    a += (f32x4){bs.x, bs.y, bs.z, bs.w};
#pragma unroll
    for (int q = 0; q < 4; ++q) if (a[q] < 0.f) a[q] = 0.f;
    h4[n * 25 + t] = make_float4(a[0], a[1], a[2], a[3]);
  }
}

// ---------------------------------------------------------------- hbar: segmented
// TWO tasks per wave (lanes 0-31 / 32-63, 25 active each): lane util 39->78%,
// wave count 410k->205k (r11: VALU-issue-bound at 47% busy, 39% lanes).
// pack2bf = v_cvt_pk_bf16_f32 (was 22 VALU ops per uint2, now ~2).
__global__ __launch_bounds__(512) void k_hseg(const int2* __restrict__ desc,
                                              const int* __restrict__ ebuf,
                                              const f32x4* __restrict__ h4,
                                              uint2* __restrict__ hbar2) {
  int wv = blockIdx.x * 8 + (threadIdx.x >> 6);
  int task = wv * 2 + ((threadIdx.x >> 5) & 1);
  if (task >= NN * R2) return;
  int n = task / R2, r = task - n * R2;
  int lane = threadIdx.x & 31;
  uint2* orow = hbar2 + (size_t)n * (KTOT / 4);   // 1056 uint2 per row
  if (r == NRELS) {   // root slot: copy h[n]
    if (lane < 25) {
      f32x4 v = h4[n * 25 + lane];
      orow[NRELS * 25 + lane] = make_uint2(pack2bf(v[0], v[1]), pack2bf(v[2], v[3]));
    }
    return;
  }
  int2 d = desc[n * NRELS + r];
  if (lane < 25) {
    f32x4 a = (f32x4){0.f, 0.f, 0.f, 0.f};
    for (int j = 0; j < d.y; ++j) {
      int s = ebuf[d.x + j] >> 6;
      a += h4[s * 25 + lane];
    }
    float coef = d.y ? 1.0f / (float)d.y : 0.f;
    a *= coef;
    orow[r * 25 + lane] = make_uint2(pack2bf(a[0], a[1]), pack2bf(a[2], a[3]));
  } else if (lane == 25 && r < 31) {
    orow[R2 * 25 + r] = make_uint2(0u, 0u);   // zero the 31-uint2 row tail
  }
}

// ---------------------------------------------------------------- split-K MFMA GEMM
// 2-phase double-buffered LDS pipeline (guide §5.5 T3-minimum).
__global__ __launch_bounds__(256) void k_gemm(const ushort* __restrict__ hbar,
                                              const ushort* __restrict__ Bt,
                                              float* __restrict__ part) {
  __shared__ char lds[2][12288];
  int t = threadIdx.x;
  int wid = t >> 6, l = t & 63;
  int lrow = l & 15, g16 = l >> 4;
  int kb0 = blockIdx.y * KB_PER;
  int row0 = blockIdx.x * 64;

  f32x4 acc[7];
#pragma unroll
  for (int j = 0; j < 7; ++j) acc[j] = (f32x4){0.f, 0.f, 0.f, 0.f};

  auto stage = [&](int p, int buf) {
    int kbg = kb0 + p;
#pragma unroll
    for (int ci = 0; ci < 3; ++ci) {
      int qb = (wid * 3 + ci) * 64;
      int q = qb + l;
      const ushort* g;
      if (q < 448) {                       // B chunk
        int col = q >> 2, c = q & 3;
        g = Bt + (size_t)col * KTOT + kbg * 32 + c * 8;
      } else if (q < 704) {                // A chunk
        int qq = q - 448;
        int row = qq >> 2, c = qq & 3;
        g = hbar + (size_t)(row0 + row) * KTOT + kbg * 32 + c * 8;
      } else {                             // pad
        g = Bt;
      }
      gload16(g, &lds[buf][(size_t)qb * 16]);
    }
  };

  stage(0, 0);
  __syncthreads();

  int cur = 0;
  for (int p = 0; p < KB_PER; ++p) {
    if (p + 1 < KB_PER) stage(p + 1, cur ^ 1);
    const char* base = lds[cur];
    bf16x8 a = *(const bf16x8*)(base + 7168 + (wid * 16 + lrow) * 64 + g16 * 16);
#pragma unroll
    for (int j = 0; j < 7; ++j) {
      bf16x8 b = *(const bf16x8*)(base + (j * 16 + lrow) * 64 + g16 * 16);
      acc[j] = __builtin_amdgcn_mfma_f32_16x16x32_bf16(a, b, acc[j], 0, 0, 0);
    }
    __syncthreads();
    cur ^= 1;
  }

  float* pp = part + (size_t)blockIdx.y * NROWS_PAD * 112;
  int srow = row0 + wid * 16 + g16 * 4;
#pragma unroll
  for (int j = 0; j < 7; ++j) {
    int col = j * 16 + lrow;
#pragma unroll
    for (int v = 0; v < 4; ++v)
      pp[(size_t)(srow + v) * 112 + col] = acc[j][v];
  }
}

// reduce partials + bias
__global__ void k_red(const float* __restrict__ part, const float* __restrict__ bias2,
                      float* __restrict__ xout) {
  int i = blockIdx.x * 256 + threadIdx.x;
  if (i >= NHTOT) return;
  int n = i / HID, c = i - n * HID;
  float s = bias2[c];
#pragma unroll
  for (int g = 0; g < SPLITK; ++g)
    s += part[(size_t)g * NROWS_PAD * 112 + (size_t)n * 112 + c];
  xout[i] = s;
}

// ---------------------------------------------------------------- rel_embedded
__global__ void k_emb(const float4* __restrict__ emb, const int* __restrict__ et,
                      float4* __restrict__ out2) {
  int i = blockIdx.x * 256 + threadIdx.x;
  if (i >= E_EDGES * 25) return;
  int e = i / 25, q = i - e * 25;
  int r = et[e];
  float4 v;
  if (r == 0) { v.x = 0.f; v.y = 0.f; v.z = 0.f; v.w = 0.f; }
  else v = emb[r * 25 + q];
  out2[i] = v;
}

// ---------------------------------------------------------------- launch
extern "C" void kernel_launch(void* const* d_in, const int* in_sizes, int n_in,
                              void* d_out, int out_size, void* d_ws, size_t ws_size,
                              hipStream_t stream) {
  (void)in_sizes; (void)n_in; (void)out_size; (void)d_ws; (void)ws_size;

  const float* comp1  = (const float*)d_in[0];
  const float* basis1 = (const float*)d_in[1];
  const float* root1  = (const float*)d_in[2];
  const float* bias1  = (const float*)d_in[3];
  const float* comp2  = (const float*)d_in[4];
  const float* basis2 = (const float*)d_in[5];
  const float* root2  = (const float*)d_in[6];
  const float* bias2  = (const float*)d_in[7];
  const float* emb    = (const float*)d_in[8];
  const int*   ei     = (const int*)d_in[9];
  const int*   et     = (const int*)d_in[10];
  const int* srcp = ei;
  const int* dstp = ei + E_EDGES;

  float* xout = (float*)d_out;
  float* scratch = xout + NHTOT;            // 32M floats (overwritten by k_emb last)
  int*   cnt_nr = (int*)scratch;            // @0          400,000
  int*   deg    = cnt_nr + 400000;          // @400,000     10,000
  int*   rowptr = deg + 10000;              // @410,000     10,004
  int*   fill_nr= rowptr + 10004;           // @420,004    400,000
  int2*  desc   = (int2*)(scratch + 820004);// @820,004    800,000 ints (even: 8B ok)
  int*   ebuf   = (int*)(scratch + 1620004);// @1,620,004  320,000 -> 1,940,004
  float* W2f    = scratch + 1940016;        // 400,000 -> 2,340,016
  ushort* Bt    = (ushort*)(scratch + 2340016);  // 236,544 f -> 2,576,560
  float* h      = scratch + 2576560;        // 1,000,000 -> 3,576,560
  uint*  W1bf   = (uint*)(scratch + 3576560);    // conv1 use: 20M
  uint*  hbar   = (uint*)(scratch + 3576560);    // conv2 use: 21,221,376 -> 24,797,936
  float* part   = scratch + 24797936;       // 4*10048*112 = 4,501,504 -> 29,299,440 OK

  // zero cnt_nr / deg / fill_nr (rowptr, desc, ebuf fully written)
  hipMemsetAsync(cnt_nr, 0, (size_t)820004 * sizeof(int), stream);
  // zero the 48 pad rows of hbar so GEMM tail reads zeros
  hipMemsetAsync((char*)hbar + (size_t)NN * KTOT * 2, 0,
                 (size_t)(NROWS_PAD - NN) * KTOT * 2, stream);

  k_count <<<(E_EDGES + 255) / 256, 256, 0, stream>>>(dstp, et, cnt_nr, deg);
  k_scan  <<<1, 256, 0, stream>>>(deg, rowptr);
  k_pnr   <<<(NN + 255) / 256, 256, 0, stream>>>(cnt_nr, rowptr, desc);
  k_bucket<<<(E_EDGES + 255) / 256, 256, 0, stream>>>(srcp, dstp, et, desc,
                                                      fill_nr, ebuf);

  k_w2 <<<(HID * HID + 255) / 256, 256, 0, stream>>>(comp2, basis2, W2f);
  k_bt <<<(112 * KTOT + 255) / 256, 256, 0, stream>>>(W2f, root2, Bt);
  k_w1b<<<dim3((NHTOT / 2 + 255) / 256, RSPLIT), 256, 0, stream>>>(comp1, basis1, W1bf);

  k_agg1<<<NN, 256, 0, stream>>>(rowptr, ebuf, cnt_nr, (const uint2*)W1bf,
                                 (const float4*)root1, (const float4*)bias1,
                                 (float4*)h);
  k_hseg<<<(NN * R2 + 15) / 16, 512, 0, stream>>>(desc, ebuf, (const f32x4*)h,
                                                  (uint2*)hbar);
  k_gemm<<<dim3(NROWS_PAD / 64, SPLITK), 256, 0, stream>>>((const ushort*)hbar, Bt, part);
  k_red <<<(NHTOT + 255) / 256, 256, 0, stream>>>(part, bias2, xout);

  k_emb<<<(E_EDGES * 25 + 255) / 256, 256, 0, stream>>>((const float4*)emb, et,
                                                        (float4*)(xout + NHTOT));
}